// Round 1
// baseline (156.842 us; speedup 1.0000x reference)
//
#include <hip/hip_runtime.h>
#include <stdint.h>

#define HW   3136
#define WID  56
#define CIN  128
#define SQ   32
#define NE   128
#define NPIX 100352   // 32*3136

// workspace layout (float offsets)
#define OFF_WSQ 0        // [ci][co] 128x32
#define OFF_WE1 4096     // [ci][co] 32x128
#define OFF_WE3 8192     // [(ci*9+tap)][co] 288x128
#define OFF_BSQ 45056    // 32
#define OFF_BE1 45088    // 128
#define OFF_BE3 45216    // 128
#define OFF_HQF 45344    // hq byte region starts at OFF_HQF*4 bytes; NPIX*32 bytes

__device__ __forceinline__ float quant_w8(float x){
  // quantize_uniform(x, 8, 1.0): grid 1/128, clamp [-1,1], cap 127/128
  float xc = fminf(fmaxf(x,-1.f),1.f);
  return fminf(rintf(xc*128.f)*0.0078125f, 0.9921875f);
}

__global__ void prep_kernel(const float* __restrict__ wsq, const float* __restrict__ bsq,
                            const float* __restrict__ we1, const float* __restrict__ be1,
                            const float* __restrict__ we3, const float* __restrict__ be3,
                            float* __restrict__ ws){
  int tid = blockIdx.x*blockDim.x+threadIdx.x;
  int nth = gridDim.x*blockDim.x;
  // w_sq: src (32,128) [co][ci] -> dst [ci*32+co]
  for (int i=tid;i<SQ*CIN;i+=nth){ int co=i>>7, ci=i&127; ws[OFF_WSQ+ci*SQ+co]=quant_w8(wsq[i]); }
  // w_e1: src (128,32) [co][ci] -> dst [ci*128+co]
  for (int i=tid;i<NE*SQ;i+=nth){ int co=i>>5, ci=i&31; ws[OFF_WE1+ci*NE+co]=quant_w8(we1[i]); }
  // w_e3: src (128,32,3,3) [co][ci][tap] -> dst [(ci*9+tap)*128+co]
  for (int i=tid;i<NE*SQ*9;i+=nth){ int co=i/288; int r=i-co*288; int ci=r/9; int t=r-ci*9;
       ws[OFF_WE3+(ci*9+t)*NE+co]=quant_w8(we3[i]); }
  for (int i=tid;i<SQ;i+=nth) ws[OFF_BSQ+i]=quant_w8(bsq[i]);
  for (int i=tid;i<NE;i+=nth) ws[OFF_BE1+i]=quant_w8(be1[i]);
  for (int i=tid;i<NE;i+=nth) ws[OFF_BE3+i]=quant_w8(be3[i]);
}

// squeeze: 1x1 conv 128->32, q8@8, relu, qact13@4, q8@4 -> store m32=32*xq as u8
__global__ __launch_bounds__(256) void squeeze_kernel(const float* __restrict__ x,
    const float* __restrict__ ws, uint8_t* __restrict__ hq){
  int pix = blockIdx.x*256+threadIdx.x;     // grid.x = 392
  int half = blockIdx.y;                     // 0/1 -> 16 couts each
  int n = pix/HW, rem = pix-n*HW;
  const float* xp = x + (size_t)n*CIN*HW + rem;
  const float* wq = ws + OFF_WSQ + half*16;
  float acc[16];
  #pragma unroll
  for (int j=0;j<16;++j) acc[j]=0.f;
  #pragma unroll 8
  for (int ci=0;ci<CIN;++ci){
    float xv = xp[(size_t)ci*HW];
    // quantize_uniform(x,8,4): grid 1/32, cap 127/32
    xv = fminf(fmaxf(xv,-4.f),4.f);
    xv = fminf(rintf(xv*32.f)*0.03125f, 3.96875f);
    const float* wrow = wq + ci*SQ;          // wave-uniform address -> s_load
    #pragma unroll
    for (int j=0;j<16;++j) acc[j]=fmaf(xv,wrow[j],acc[j]);
  }
  uint32_t pk[4];
  #pragma unroll
  for (int q=0;q<4;++q){
    uint32_t p=0;
    #pragma unroll
    for (int b=0;b<4;++b){
      int j=q*4+b;
      float y = acc[j] + ws[OFF_BSQ+half*16+j];
      y = fminf(fmaxf(y,-8.f),8.f);                 // q8 clip 8: grid 1/16
      y = fminf(rintf(y*16.f)*0.0625f, 7.9375f);
      y = fmaxf(y,0.f);                             // relu
      y = fminf(y,4.f);                             // qact13@4 (round exact on 1/16 grid)
      y = fminf(y,0.9998779296875f);                //   cap 8191/8192
      uint32_t m = (uint32_t)(int)rintf(y*32.f);    // q8@4 -> m32 in {0,2,...,32}
      p |= m<<(8*b);
    }
    pk[q]=p;
  }
  *(uint4*)(hq + (size_t)pix*32 + half*16) = make_uint4(pk[0],pk[1],pk[2],pk[3]);
}

// expand1: 1x1 conv 32->128, q8@8, relu -> out channels [0,128)
__global__ __launch_bounds__(256) void expand1_kernel(const uint8_t* __restrict__ hq,
    const float* __restrict__ ws, float* __restrict__ out){
  int pix = blockIdx.x*256+threadIdx.x;
  int chunk = blockIdx.y;                    // 0..3 -> 32 couts each
  int n = pix/HW, rem = pix-n*HW;
  const uint4* hv = (const uint4*)(hq + (size_t)pix*32);
  uint4 a = hv[0], b4 = hv[1];
  uint32_t hwd[8] = {a.x,a.y,a.z,a.w,b4.x,b4.y,b4.z,b4.w};
  float acc[32];
  #pragma unroll
  for (int j=0;j<32;++j) acc[j]=0.f;
  const float* wq = ws + OFF_WE1 + chunk*32;
  #pragma unroll 8
  for (int ci=0;ci<SQ;++ci){
    float xv = (float)((hwd[ci>>2]>>((ci&3)*8))&0xffu);   // m32 in [0,32]
    const float* wrow = wq + ci*NE;
    #pragma unroll
    for (int j=0;j<32;++j) acc[j]=fmaf(xv,wrow[j],acc[j]);
  }
  float* op = out + ((size_t)n*256 + chunk*32)*HW + rem;
  #pragma unroll
  for (int j=0;j<32;++j){
    float y = acc[j]*0.03125f + ws[OFF_BE1+chunk*32+j];   // fold xq=m32/32
    y = fminf(fmaxf(y,-8.f),8.f);
    y = fminf(rintf(y*16.f)*0.0625f, 7.9375f);
    y = fmaxf(y,0.f);
    op[(size_t)j*HW] = y;
  }
}

// expand3: 3x3 conv 32->128 pad=1, q8@8, relu -> out channels [128,256)
__global__ __launch_bounds__(256) void expand3_kernel(const uint8_t* __restrict__ hq,
    const float* __restrict__ ws, float* __restrict__ out){
  int pix = blockIdx.x*256+threadIdx.x;
  int chunk = blockIdx.y;                    // 0..3 -> 32 couts each
  int n = pix/HW, rem = pix-n*HW;
  int yy = rem/WID, xx = rem-yy*WID;
  uint32_t nb[9][8];
  #pragma unroll
  for (int t=0;t<9;++t){
    int dy=t/3-1, dx=t%3-1;
    int y2=yy+dy, x2=xx+dx;
    bool ok = ((unsigned)y2<56u) && ((unsigned)x2<56u);
    if (ok){
      const uint4* hv=(const uint4*)(hq + ((size_t)(n*HW + y2*WID + x2))*32);
      uint4 a=hv[0], b4=hv[1];
      nb[t][0]=a.x; nb[t][1]=a.y; nb[t][2]=a.z; nb[t][3]=a.w;
      nb[t][4]=b4.x; nb[t][5]=b4.y; nb[t][6]=b4.z; nb[t][7]=b4.w;
    } else {
      #pragma unroll
      for(int k2=0;k2<8;++k2) nb[t][k2]=0u;
    }
  }
  float acc[32];
  #pragma unroll
  for (int j=0;j<32;++j) acc[j]=0.f;
  const float* wq = ws + OFF_WE3 + chunk*32;
  #pragma unroll 2
  for (int ci=0;ci<SQ;++ci){
    float f[9];
    #pragma unroll
    for (int t=0;t<9;++t) f[t] = (float)((nb[t][ci>>2]>>((ci&3)*8))&0xffu);
    #pragma unroll
    for (int t=0;t<9;++t){
      const float* wrow = wq + (ci*9+t)*NE;  // wave-uniform -> s_load
      #pragma unroll
      for (int j=0;j<32;++j) acc[j]=fmaf(f[t],wrow[j],acc[j]);
    }
  }
  float* op = out + ((size_t)n*256 + 128 + chunk*32)*HW + rem;
  #pragma unroll
  for (int j=0;j<32;++j){
    float y = acc[j]*0.03125f + ws[OFF_BE3+chunk*32+j];
    y = fminf(fmaxf(y,-8.f),8.f);
    y = fminf(rintf(y*16.f)*0.0625f, 7.9375f);
    y = fmaxf(y,0.f);
    op[(size_t)j*HW] = y;
  }
}

extern "C" void kernel_launch(void* const* d_in, const int* in_sizes, int n_in,
                              void* d_out, int out_size, void* d_ws, size_t ws_size,
                              hipStream_t stream){
  const float* x   = (const float*)d_in[0];
  const float* wsq = (const float*)d_in[1];
  const float* bsq = (const float*)d_in[2];
  const float* we1 = (const float*)d_in[3];
  const float* be1 = (const float*)d_in[4];
  const float* we3 = (const float*)d_in[5];
  const float* be3 = (const float*)d_in[6];
  float* out = (float*)d_out;
  float* ws  = (float*)d_ws;
  uint8_t* hq = (uint8_t*)d_ws + (size_t)OFF_HQF*4;

  hipLaunchKernelGGL(prep_kernel, dim3(64), dim3(256), 0, stream,
                     wsq, bsq, we1, be1, we3, be3, ws);
  hipLaunchKernelGGL(squeeze_kernel, dim3(NPIX/256, 2), dim3(256), 0, stream, x, ws, hq);
  hipLaunchKernelGGL(expand1_kernel, dim3(NPIX/256, 4), dim3(256), 0, stream, hq, ws, out);
  hipLaunchKernelGGL(expand3_kernel, dim3(NPIX/256, 4), dim3(256), 0, stream, hq, ws, out);
}

// Round 2
// 54.143 us; speedup vs baseline: 2.8968x; 2.8968x over previous
//
#include <hip/hip_runtime.h>
#include <stdint.h>

typedef __bf16 bf16x8 __attribute__((ext_vector_type(8)));
typedef float  f32x4  __attribute__((ext_vector_type(4)));

#define HW   3136
#define WID  56
#define CIN  128
#define SQ   32
#define NPIX 100352   // 32*3136

// workspace layout
#define OFF_WSQ 0              // f32 [ci][co] 128x32
#define OFF_BSQ 4096           // f32 [32]
#define OFF_BE  4128           // f32 [256] (e1 then e3)
#define WE1F_BYTES_OFF 17536   // bf16 frags [8 mf][64 lane][8] = 8192 B
#define WE3F_BYTES_OFF 25728   // bf16 frags [8 mf][9 tap][64 lane][8] = 73728 B
#define HQ_BYTES_OFF   99456   // u8 [NPIX][32]

__device__ __forceinline__ float quant_w8(float x){
  float xc = fminf(fmaxf(x,-1.f),1.f);
  return fminf(rintf(xc*128.f)*0.0078125f, 0.9921875f);
}
// weight as integer n = 128*wq in [-128,127], stored as exact bf16
__device__ __forceinline__ ushort wq_int_bf16(float x){
  float xc = fminf(fmaxf(x,-1.f),1.f);
  float n = fminf(rintf(xc*128.f), 127.f);
  return (ushort)(__float_as_uint(n)>>16);
}
__device__ __forceinline__ uint pack2(uint k0, uint k1){
  return (__float_as_uint((float)k0)>>16) | (__float_as_uint((float)k1)&0xffff0000u);
}

__global__ void prep_kernel(const float* __restrict__ wsq, const float* __restrict__ bsq,
                            const float* __restrict__ we1, const float* __restrict__ be1,
                            const float* __restrict__ we3, const float* __restrict__ be3,
                            float* __restrict__ ws){
  int tid = blockIdx.x*blockDim.x+threadIdx.x;
  int nth = gridDim.x*blockDim.x;
  ushort* we1f = (ushort*)((char*)ws + WE1F_BYTES_OFF);
  ushort* we3f = (ushort*)((char*)ws + WE3F_BYTES_OFF);
  // squeeze weights [ci][co] f32
  for (int i=tid;i<SQ*CIN;i+=nth){ int co=i>>7, ci=i&127; ws[OFF_WSQ+ci*SQ+co]=quant_w8(wsq[i]); }
  for (int i=tid;i<SQ;i+=nth) ws[OFF_BSQ+i]=quant_w8(bsq[i]);
  for (int i=tid;i<256;i+=nth) ws[OFF_BE+i] = (i<128)? quant_w8(be1[i]) : quant_w8(be3[i-128]);
  // e1 A-fragments: A[co=mf*16+(l&15)][k=ci=(l>>4)*8+j]
  for (int i=tid;i<4096;i+=nth){
    int mf=i>>9, l=(i>>3)&63, j=i&7;
    int co=mf*16+(l&15), ci=(l>>4)*8+j;
    we1f[i] = wq_int_bf16(we1[co*SQ+ci]);
  }
  // e3 A-fragments per tap: k within tap = ci
  for (int i=tid;i<36864;i+=nth){
    int mf=i/4608, r=i-mf*4608, t=r>>9, l=(r>>3)&63, j=r&7;
    int co=mf*16+(l&15), ci=(l>>4)*8+j;
    we3f[i] = wq_int_bf16(we3[(co*SQ+ci)*9+t]);
  }
}

// squeeze: 1x1 conv 128->32, q8@8, relu, qact13@4, q8@4 -> store m32 (=32*xq) as u8
__global__ __launch_bounds__(256) void squeeze_kernel(const float* __restrict__ x,
    const float* __restrict__ ws, uint8_t* __restrict__ hq){
  int pix = blockIdx.x*256+threadIdx.x;
  int half = blockIdx.y;
  int n = pix/HW, rem = pix-n*HW;
  const float* xp = x + (size_t)n*CIN*HW + rem;
  const float* wq = ws + OFF_WSQ + half*16;
  float acc[16];
  #pragma unroll
  for (int j=0;j<16;++j) acc[j]=0.f;
  #pragma unroll 8
  for (int ci=0;ci<CIN;++ci){
    float xv = xp[(size_t)ci*HW];
    xv = fminf(fmaxf(xv,-4.f),4.f);
    xv = fminf(rintf(xv*32.f)*0.03125f, 3.96875f);
    const float* wrow = wq + ci*SQ;
    #pragma unroll
    for (int j=0;j<16;++j) acc[j]=fmaf(xv,wrow[j],acc[j]);
  }
  uint32_t pk[4];
  #pragma unroll
  for (int q=0;q<4;++q){
    uint32_t p=0;
    #pragma unroll
    for (int b=0;b<4;++b){
      int j=q*4+b;
      float y = acc[j] + ws[OFF_BSQ+half*16+j];
      y = fminf(fmaxf(y,-8.f),8.f);
      y = fminf(rintf(y*16.f)*0.0625f, 7.9375f);
      y = fmaxf(y,0.f);
      y = fminf(y,4.f);
      y = fminf(y,0.9998779296875f);
      uint32_t m = (uint32_t)(int)rintf(y*32.f);
      p |= m<<(8*b);
    }
    pk[q]=p;
  }
  *(uint4*)(hq + (size_t)pix*32 + half*16) = make_uint4(pk[0],pk[1],pk[2],pk[3]);
}

// fused expand: e1 (out ch 0..127) + e3 (out ch 128..255) via bf16 MFMA implicit GEMM.
// WG: one image n, 2 output rows (112 pixels). 4 waves; wave w -> m-frags {w,w+4,w+8,w+12}.
__global__ __launch_bounds__(256) void expand_kernel(const uint8_t* __restrict__ hq,
    const float* __restrict__ ws, float* __restrict__ out){
  __shared__ uint4 lds4[232*4];   // h halo tile: [pix 4x58][ci 32] bf16, 16B-chunk XOR swizzle
  int br = blockIdx.x;            // 0..27 row block
  int n  = blockIdx.y;            // 0..31
  int tid = threadIdx.x;

  if (tid < 232){
    int r = tid/58, c = tid - r*58;
    int gy = br*2 + r - 1, gx = c - 1;
    uint4 v0, v1;
    if ((unsigned)gy < 56u && (unsigned)gx < 56u){
      const uint4* src = (const uint4*)(hq + ((size_t)(n*HW + gy*WID + gx))*32);
      v0 = src[0]; v1 = src[1];
    } else { v0 = make_uint4(0,0,0,0); v1 = v0; }
    uint w8[8] = {v0.x,v0.y,v0.z,v0.w,v1.x,v1.y,v1.z,v1.w};
    #pragma unroll
    for (int cc=0;cc<4;++cc){
      uint a = w8[cc*2], b = w8[cc*2+1];
      uint4 o;
      o.x = pack2(a&255u, (a>>8)&255u);
      o.y = pack2((a>>16)&255u, a>>24);
      o.z = pack2(b&255u, (b>>8)&255u);
      o.w = pack2((b>>16)&255u, b>>24);
      lds4[tid*4 + (cc ^ ((tid>>1)&3))] = o;
    }
  }
  __syncthreads();

  int lane = tid&63, wid = tid>>6;
  int colg = lane&15, kg = lane>>4;
  int baseh[7];
  #pragma unroll
  for (int nf=0;nf<7;++nf){
    int p = nf*16 + colg;
    int row = p/56, xx = p - row*56;
    baseh[nf] = (row+1)*58 + xx + 1;
  }
  float bias_v[4][4];
  #pragma unroll
  for (int mi=0;mi<4;++mi)
    #pragma unroll
    for (int r=0;r<4;++r)
      bias_v[mi][r] = ws[OFF_BE + (wid+mi*4)*16 + kg*4 + r];

  f32x4 acc[4][7];
  #pragma unroll
  for (int mi=0;mi<4;++mi)
    #pragma unroll
    for (int nf=0;nf<7;++nf)
      acc[mi][nf] = (f32x4){0.f,0.f,0.f,0.f};

  const bf16x8* we1f = (const bf16x8*)((const char*)ws + WE1F_BYTES_OFF);
  const bf16x8* we3f = (const bf16x8*)((const char*)ws + WE3F_BYTES_OFF);
  const bf16x8* lbase = (const bf16x8*)lds4;

  #pragma unroll
  for (int t=0;t<9;++t){
    int off = (t/3 - 1)*58 + (t%3 - 1);
    bf16x8 B[7];
    #pragma unroll
    for (int nf=0;nf<7;++nf){
      int ph = baseh[nf] + off;
      int idx = ph*4 + (kg ^ ((ph>>1)&3));
      B[nf] = lbase[idx];
    }
    bf16x8 A2 = we3f[(wid*9+t)*64 + lane];
    bf16x8 A3 = we3f[((wid+4)*9+t)*64 + lane];
    #pragma unroll
    for (int nf=0;nf<7;++nf){
      acc[2][nf] = __builtin_amdgcn_mfma_f32_16x16x32_bf16(A2, B[nf], acc[2][nf], 0,0,0);
      acc[3][nf] = __builtin_amdgcn_mfma_f32_16x16x32_bf16(A3, B[nf], acc[3][nf], 0,0,0);
    }
    if (t==4){
      bf16x8 A0 = we1f[wid*64 + lane];
      bf16x8 A1 = we1f[(wid+4)*64 + lane];
      #pragma unroll
      for (int nf=0;nf<7;++nf){
        acc[0][nf] = __builtin_amdgcn_mfma_f32_16x16x32_bf16(A0, B[nf], acc[0][nf], 0,0,0);
        acc[1][nf] = __builtin_amdgcn_mfma_f32_16x16x32_bf16(A1, B[nf], acc[1][nf], 0,0,0);
      }
    }
  }

  // epilogue: y = acc/4096 + bias; q8@8; relu.  C-frag: col=lane&15 (pixel), row=kg*4+r (cout)
  #pragma unroll
  for (int mi=0;mi<4;++mi){
    int co = (wid+mi*4)*16 + kg*4;
    #pragma unroll
    for (int nf=0;nf<7;++nf){
      int opix = br*112 + nf*16 + colg;
      float* op = out + (size_t)(n*256+co)*HW + opix;
      #pragma unroll
      for (int r=0;r<4;++r){
        float y = fmaf(acc[mi][nf][r], 0.000244140625f, bias_v[mi][r]);
        y = fminf(fmaxf(y,-8.f),8.f);
        y = fminf(rintf(y*16.f)*0.0625f, 7.9375f);
        y = fmaxf(y,0.f);
        op[(size_t)r*HW] = y;
      }
    }
  }
}

extern "C" void kernel_launch(void* const* d_in, const int* in_sizes, int n_in,
                              void* d_out, int out_size, void* d_ws, size_t ws_size,
                              hipStream_t stream){
  const float* x   = (const float*)d_in[0];
  const float* wsq = (const float*)d_in[1];
  const float* bsq = (const float*)d_in[2];
  const float* we1 = (const float*)d_in[3];
  const float* be1 = (const float*)d_in[4];
  const float* we3 = (const float*)d_in[5];
  const float* be3 = (const float*)d_in[6];
  float* out = (float*)d_out;
  float* ws  = (float*)d_ws;
  uint8_t* hq = (uint8_t*)d_ws + HQ_BYTES_OFF;

  hipLaunchKernelGGL(prep_kernel, dim3(64), dim3(256), 0, stream,
                     wsq, bsq, we1, be1, we3, be3, ws);
  hipLaunchKernelGGL(squeeze_kernel, dim3(NPIX/256, 2), dim3(256), 0, stream, x, ws, hq);
  hipLaunchKernelGGL(expand_kernel, dim3(28, 32), dim3(256), 0, stream, hq, ws, out);
}